// Round 6
// baseline (95.728 us; speedup 1.0000x reference)
//
#include <hip/hip_runtime.h>

// Round 23: intra-wave 2-deep pipeline (T15-style). Evidence: r19 (barriers)
// neutral, r22 (half LDS traffic) +1.6us only -> fa_split (~35us) is NOT
// throughput-bound (pipe floors ~12us); it's serialized on the per-tile chain
// S->exp->cvt->PV at 2-4 waves/SIMD. Fix: overlap group n+1's S-MFMAs with
// group n's exp/P/PV in one BB (independent chains; MFMA pipe || trans/VALU).
// 32q/wave (S-state = 1 f32x16 -> 2-deep fits ~165 VGPR), K/V dbuf, 2
// barriers/tile between non-conflicting regions. Math bit-identical to
// r18/r22 (swapped QK^T, in-reg P via cvt_pk+permlane32_swap, mask folded
// into prepass). ~46-50us harness fill untouchable.
// C/D map: col=lane&31, row=(reg&3)+8(reg>>2)+4(lane>>5).
// B=4, Lq=Lk=4096, D=64, fp32 I/O, int32 key-padding mask.

#define B_N    4
#define L      4096
#define DH     64
#define TILE_K 64
#define KPAD   72
#define SPLIT  8
#define SLAB   (L / SPLIT)       // 512 keys per slab
#define TILES  (SLAB / TILE_K)   // 8 tiles per slab
#define QSCALE 0.18033688f       // 0.125 * log2(e); p = 2^(Qs K^T)

typedef unsigned short ushort8_ma __attribute__((ext_vector_type(8), may_alias));
typedef unsigned short ushort4_ma __attribute__((ext_vector_type(4), may_alias));
typedef float          f32x4_ma   __attribute__((ext_vector_type(4), may_alias));
typedef short          short8     __attribute__((ext_vector_type(8)));
typedef float          f32x16     __attribute__((ext_vector_type(16)));
typedef unsigned int   uint2_ev   __attribute__((ext_vector_type(2)));

union v8cast  { ushort8_ma u; short8 s; };
union pk4cast { unsigned int u[4]; short8 s; };

static __device__ __forceinline__ short8 ld8(const unsigned short* p) {
    v8cast x; x.u = *(const ushort8_ma*)p; return x.s;
}
static __device__ __forceinline__ unsigned short bf16rne(float f) {
    union { float f; unsigned u; } x; x.f = f;
    unsigned r = x.u + 0x7fffu + ((x.u >> 16) & 1u);
    return (unsigned short)(r >> 16);
}
static __device__ __forceinline__ float bf16tof(unsigned short u) {
    union { unsigned u; float f; } x; x.u = (unsigned)u << 16; return x.f;
}
static __device__ __forceinline__ float fast_exp2(float x) {
    return __builtin_amdgcn_exp2f(x);   // native v_exp_f32 (base-2)
}
static __device__ __forceinline__ unsigned cvt_pk_bf16(float lo, float hi) {
    unsigned r;                          // no builtin on gfx950 (m240) -> asm
    asm("v_cvt_pk_bf16_f32 %0, %1, %2" : "=v"(r) : "v"(lo), "v"(hi));
    return r;
}
// P A-fragment for one 8-value half of p (keys kk*16..+15): 4 cvt + 2 permlane.
static __device__ __forceinline__ short8 build_P(const f32x16& p, int b0) {
    unsigned A0 = cvt_pk_bf16(p[b0 + 0], p[b0 + 1]);
    unsigned A1 = cvt_pk_bf16(p[b0 + 2], p[b0 + 3]);
    unsigned B0 = cvt_pk_bf16(p[b0 + 4], p[b0 + 5]);
    unsigned B1 = cvt_pk_bf16(p[b0 + 6], p[b0 + 7]);
    uint2_ev r02 = __builtin_amdgcn_permlane32_swap(A0, B0, false, false);
    uint2_ev r13 = __builtin_amdgcn_permlane32_swap(A1, B1, false, false);
    pk4cast P;
    P.u[0] = r02[0]; P.u[1] = r13[0];   // j0..3 (hw'=0 source)
    P.u[2] = r02[1]; P.u[3] = r13[1];   // j4..7 (hw'=1 source)
    return P.s;
}

// ---- prepass: 16 rows/block: Qb=bf16(Q*QSCALE), Kb=bf16(K)*maskvalid,
//      Vt=bf16(V)*maskvalid transposed [b][d][key]. Masked key rows zeroed so
//      the main loop needs no mask: s==0 -> p==1, V==0 -> 0 numerator. ----
__global__ __launch_bounds__(256)
void prepass3(const float* __restrict__ Q, const float* __restrict__ K,
              const float* __restrict__ V, const int* __restrict__ M,
              unsigned short* __restrict__ Qb, unsigned short* __restrict__ Kb,
              unsigned short* __restrict__ Vt)
{
    __shared__ unsigned short t[64][20];   // [d][key16 + pad]
    const int b  = blockIdx.y;
    const int r0 = blockIdx.x * 16;
    const size_t base = ((size_t)b * L + r0) * DH;

    {
        int i = threadIdx.x;               // 256 = 16 rows x 16 float4
        int row = i >> 4, d0 = (i & 15) * 4;
        size_t off = base + (size_t)row * DH + d0;
        f32x4_ma q = *(const f32x4_ma*)(Q + off);
        f32x4_ma k = *(const f32x4_ma*)(K + off);
        f32x4_ma v = *(const f32x4_ma*)(V + off);
        const float zf = (M[(size_t)b * L + r0 + row] == 0) ? 0.f : 1.f;
        ushort4_ma qo, ko;
        #pragma unroll
        for (int j = 0; j < 4; ++j) {
            qo[j] = bf16rne(q[j] * QSCALE);
            ko[j] = bf16rne(k[j] * zf);
            t[d0 + j][row] = bf16rne(v[j] * zf);
        }
        *(ushort4_ma*)(Qb + off) = qo;
        *(ushort4_ma*)(Kb + off) = ko;
    }
    __syncthreads();
    {
        int i = threadIdx.x;               // 256 = 64 d x 4 ushort4
        int d = i >> 2, k4 = (i & 3) * 4;
        ushort4_ma vo = { t[d][k4], t[d][k4 + 1], t[d][k4 + 2], t[d][k4 + 3] };
        *(ushort4_ma*)(Vt + ((size_t)b * DH + d) * L + r0 + k4) = vo;
    }
}

// ---- split-K main: 32x32x16 MFMA, 256 threads (4 waves x 32 q-rows),
//      2-deep S pipeline across 32-key groups ----
__global__ __launch_bounds__(256, 2)
void fa_pipe32(const unsigned short* __restrict__ Qb,
               const unsigned short* __restrict__ Kb,
               const unsigned short* __restrict__ Vt,
               const int*            __restrict__ Mk,
               unsigned short* __restrict__ ACCp, float* __restrict__ Lp)
{
    __shared__ unsigned short Kl[2][TILE_K * KPAD];   // 2 x 9216 B [key][d]
    __shared__ unsigned short Vl[2][DH * KPAD];       // 2 x 9216 B [d][key]
    __shared__ int            cntw[4];                // per-wave masked counts
    // 36880 B/block

    const int tid  = threadIdx.x;
    const int wave = tid >> 6;
    const int lane = tid & 63;
    const int l32  = lane & 31;
    const int hw   = lane >> 5;            // half-wave index

    const int b      = blockIdx.y & (B_N - 1);
    const int slab   = blockIdx.y >> 2;
    const int qblock = blockIdx.x * 128;   // 4 waves x 32 rows
    const int kbase  = slab * SLAB;
    const int qbase  = qblock + wave * 32;

    // Q fragments (B operand): lane l32 -> q-col, k = hw*8+j
    short8 bQ0, bQ1, bQ2, bQ3;
    {
        const unsigned short* qp = Qb + ((size_t)b * L + qbase + l32) * DH + hw * 8;
        bQ0 = ld8(qp);      bQ1 = ld8(qp + 16);
        bQ2 = ld8(qp + 32); bQ3 = ld8(qp + 48);
    }

    const unsigned short* Kbb = Kb + (size_t)b * L * DH;
    const unsigned short* Vtb = Vt + (size_t)b * DH * L;
    const int*            Mb  = Mk + (size_t)b * L;

    // staging: 2 chunks of 8 bf16 per thread for K and for V (r12-validated)
    const int c1 = tid + 256;
    const int r0 = tid >> 3, d0 = (tid & 7) * 8;
    const int r1 = c1 >> 3,  d1 = (c1 & 7) * 8;

    ushort8_ma kr0, kr1, vr0, vr1;

    // tile 0 -> buf0 directly
    kr0 = *(const ushort8_ma*)(Kbb + (size_t)(kbase + r0) * DH + d0);
    kr1 = *(const ushort8_ma*)(Kbb + (size_t)(kbase + r1) * DH + d1);
    vr0 = *(const ushort8_ma*)(Vtb + (size_t)r0 * L + kbase + d0);
    vr1 = *(const ushort8_ma*)(Vtb + (size_t)r1 * L + kbase + d1);
    const int m0 = Mb[kbase + 2 * tid];
    const int m1 = Mb[kbase + 2 * tid + 1];
    *(ushort8_ma*)(&Kl[0][r0 * KPAD + d0]) = kr0;
    *(ushort8_ma*)(&Kl[0][r1 * KPAD + d1]) = kr1;
    *(ushort8_ma*)(&Vl[0][r0 * KPAD + d0]) = vr0;
    *(ushort8_ma*)(&Vl[0][r1 * KPAD + d1]) = vr1;
    {
        unsigned long long bm0 = __ballot(m0 == 0);
        unsigned long long bm1 = __ballot(m1 == 0);
        if (lane == 0) cntw[wave] = __popcll(bm0) + __popcll(bm1);
    }
    // preload tile 1 into staging regs (written at iter 0's staging phase)
    {
        const int k0n = kbase + TILE_K;
        kr0 = *(const ushort8_ma*)(Kbb + (size_t)(k0n + r0) * DH + d0);
        kr1 = *(const ushort8_ma*)(Kbb + (size_t)(k0n + r1) * DH + d1);
        vr0 = *(const ushort8_ma*)(Vtb + (size_t)r0 * L + k0n + d0);
        vr1 = *(const ushort8_ma*)(Vtb + (size_t)r1 * L + k0n + d1);
    }
    __syncthreads();

    f32x16 acc0 = {0}, acc1 = {0};
    float rs0 = 0.f, rs1 = 0.f, rs2 = 0.f, rs3 = 0.f;   // 4-way rowsum chains

    // prologue: S(g0, t=0) -> sA
    f32x16 sA, sB;
    {
        const unsigned short* kp = &Kl[0][l32 * KPAD + hw * 8];
        f32x16 s = {0};
        s = __builtin_amdgcn_mfma_f32_32x32x16_bf16(ld8(kp),      bQ0, s, 0, 0, 0);
        s = __builtin_amdgcn_mfma_f32_32x32x16_bf16(ld8(kp + 16), bQ1, s, 0, 0, 0);
        s = __builtin_amdgcn_mfma_f32_32x32x16_bf16(ld8(kp + 32), bQ2, s, 0, 0, 0);
        s = __builtin_amdgcn_mfma_f32_32x32x16_bf16(ld8(kp + 48), bQ3, s, 0, 0, 0);
        sA = s;
    }

    #pragma unroll
    for (int t = 0; t < TILES; ++t) {
        const int cur = t & 1, nxt = cur ^ 1;

        // ---- phase A: S(g1,t) -> sB  ||  exp/P/PV(g0,t) — one BB, the
        //      scheduler interleaves MFMA(S) with trans/VALU(exp,P) ----
        {
            const unsigned short* kp = &Kl[cur][(32 + l32) * KPAD + hw * 8];
            f32x16 s = {0};
            s = __builtin_amdgcn_mfma_f32_32x32x16_bf16(ld8(kp),      bQ0, s, 0, 0, 0);
            s = __builtin_amdgcn_mfma_f32_32x32x16_bf16(ld8(kp + 16), bQ1, s, 0, 0, 0);
            s = __builtin_amdgcn_mfma_f32_32x32x16_bf16(ld8(kp + 32), bQ2, s, 0, 0, 0);
            s = __builtin_amdgcn_mfma_f32_32x32x16_bf16(ld8(kp + 48), bQ3, s, 0, 0, 0);
            sB = s;
        }
        {
            // g0: keys 0..31 of this tile; kk = 0,1; V from Vl[cur]
            f32x16 p;
            #pragma unroll
            for (int r = 0; r < 16; r += 4) {
                p[r + 0] = fast_exp2(sA[r + 0]); rs0 += p[r + 0];
                p[r + 1] = fast_exp2(sA[r + 1]); rs1 += p[r + 1];
                p[r + 2] = fast_exp2(sA[r + 2]); rs2 += p[r + 2];
                p[r + 3] = fast_exp2(sA[r + 3]); rs3 += p[r + 3];
            }
            const unsigned short* vp = &Vl[cur][l32 * KPAD + hw * 8];
            short8 v00 = ld8(vp);                  // kk=0, d-low
            short8 v10 = ld8(vp + 32 * KPAD);      // kk=0, d-high
            short8 v01 = ld8(vp + 16);             // kk=1, d-low
            short8 v11 = ld8(vp + 16 + 32 * KPAD); // kk=1, d-high
            short8 P0 = build_P(p, 0);
            acc0 = __builtin_amdgcn_mfma_f32_32x32x16_bf16(P0, v00, acc0, 0, 0, 0);
            acc1 = __builtin_amdgcn_mfma_f32_32x32x16_bf16(P0, v10, acc1, 0, 0, 0);
            short8 P1 = build_P(p, 8);
            acc0 = __builtin_amdgcn_mfma_f32_32x32x16_bf16(P1, v01, acc0, 0, 0, 0);
            acc1 = __builtin_amdgcn_mfma_f32_32x32x16_bf16(P1, v11, acc1, 0, 0, 0);
        }

        // ---- phase B: stage tile t+1 (regs loaded one tile ago) ----
        if (t < TILES - 1) {
            __syncthreads();               // readers of buf[nxt] (tile t-1) done
            *(ushort8_ma*)(&Kl[nxt][r0 * KPAD + d0]) = kr0;
            *(ushort8_ma*)(&Kl[nxt][r1 * KPAD + d1]) = kr1;
            *(ushort8_ma*)(&Vl[nxt][r0 * KPAD + d0]) = vr0;
            *(ushort8_ma*)(&Vl[nxt][r1 * KPAD + d1]) = vr1;
            __syncthreads();               // writes visible
            if (t < TILES - 2) {           // issue t+2 loads (one-tile cover)
                const int k0n = kbase + (t + 2) * TILE_K;
                kr0 = *(const ushort8_ma*)(Kbb + (size_t)(k0n + r0) * DH + d0);
                kr1 = *(const ushort8_ma*)(Kbb + (size_t)(k0n + r1) * DH + d1);
                vr0 = *(const ushort8_ma*)(Vtb + (size_t)r0 * L + k0n + d0);
                vr1 = *(const ushort8_ma*)(Vtb + (size_t)r1 * L + k0n + d1);
            }
        }

        // ---- phase D: S(g0,t+1) -> sA  ||  exp/P/PV(g1,t) ----
        if (t < TILES - 1) {
            const unsigned short* kp = &Kl[nxt][l32 * KPAD + hw * 8];
            f32x16 s = {0};
            s = __builtin_amdgcn_mfma_f32_32x32x16_bf16(ld8(kp),      bQ0, s, 0, 0, 0);
            s = __builtin_amdgcn_mfma_f32_32x32x16_bf16(ld8(kp + 16), bQ1, s, 0, 0, 0);
            s = __builtin_amdgcn_mfma_f32_32x32x16_bf16(ld8(kp + 32), bQ2, s, 0, 0, 0);
            s = __builtin_amdgcn_mfma_f32_32x32x16_bf16(ld8(kp + 48), bQ3, s, 0, 0, 0);
            sA = s;
        }
        {
            // g1: keys 32..63 of tile t; kk = 2,3; V from Vl[cur]
            f32x16 p;
            #pragma unroll
            for (int r = 0; r < 16; r += 4) {
                p[r + 0] = fast_exp2(sB[r + 0]); rs0 += p[r + 0];
                p[r + 1] = fast_exp2(sB[r + 1]); rs1 += p[r + 1];
                p[r + 2] = fast_exp2(sB[r + 2]); rs2 += p[r + 2];
                p[r + 3] = fast_exp2(sB[r + 3]); rs3 += p[r + 3];
            }
            const unsigned short* vp = &Vl[cur][l32 * KPAD + 32 + hw * 8];
            short8 v02 = ld8(vp);                  // kk=2, d-low
            short8 v12 = ld8(vp + 32 * KPAD);      // kk=2, d-high
            short8 v03 = ld8(vp + 16);             // kk=3, d-low
            short8 v13 = ld8(vp + 16 + 32 * KPAD); // kk=3, d-high
            short8 P0 = build_P(p, 0);
            acc0 = __builtin_amdgcn_mfma_f32_32x32x16_bf16(P0, v02, acc0, 0, 0, 0);
            acc1 = __builtin_amdgcn_mfma_f32_32x32x16_bf16(P0, v12, acc1, 0, 0, 0);
            short8 P1 = build_P(p, 8);
            acc0 = __builtin_amdgcn_mfma_f32_32x32x16_bf16(P1, v03, acc0, 0, 0, 0);
            acc1 = __builtin_amdgcn_mfma_f32_32x32x16_bf16(P1, v13, acc1, 0, 0, 0);
        }
    }

    // epilogue: rowsum = in-lane sum + cross-halfwave add; subtract the slab's
    // masked-key count (each masked key contributed exactly 1.0).
    float rs = (rs0 + rs1) + (rs2 + rs3);
    rs += __shfl_xor(rs, 32);
    const float scnt = (float)(cntw[0] + cntw[1] + cntw[2] + cntw[3]);
    const size_t pbase = ((size_t)(slab * B_N + b)) * L;
    #pragma unroll
    for (int reg = 0; reg < 16; ++reg) {
        int row  = (reg & 3) + 8 * (reg >> 2) + 4 * hw;
        int qrow = qbase + row;
        unsigned short* ap = ACCp + (pbase + qrow) * DH;
        ap[l32]      = bf16rne(acc0[reg]);
        ap[32 + l32] = bf16rne(acc1[reg]);
    }
    if (hw == 0)
        Lp[pbase + qbase + l32] = rs - scnt;
}

// ---- combine: plain sums over bf16 partials (fixed-m needs no max) ----
__global__ __launch_bounds__(256)
void fa_combine(const unsigned short* __restrict__ ACCp,
                const float* __restrict__ Lp, float* __restrict__ O)
{
    const int b    = blockIdx.y;
    const int qrow = blockIdx.x * 4 + (threadIdx.x >> 6);
    const int d    = threadIdx.x & 63;

    float lsum = 0.f, o = 0.f;
    #pragma unroll
    for (int s = 0; s < SPLIT; ++s) {
        lsum += Lp[((size_t)(s * B_N + b)) * L + qrow];
        o    += bf16tof(ACCp[(((size_t)(s * B_N + b)) * L + qrow) * DH + d]);
    }
    O[((size_t)b * L + qrow) * DH + d] = o / fmaxf(lsum, 1e-20f);
}

// ---- fallback: validated scalar kernel ----
#define TK  64
#define RW  4
#define RB  16
#define KST 67

__global__ __launch_bounds__(256)
void fa_scalar(const float* __restrict__ Q, const float* __restrict__ K,
               const float* __restrict__ V, const int* __restrict__ Mk,
               float* __restrict__ O)
{
    __shared__ float Kt[TK][KST];
    __shared__ float Vts[DH][KST];
    __shared__ float Qs[RB][DH];
    __shared__ float Ps[4][RW][TK];
    __shared__ float Bs[TK];

    const int tid = threadIdx.x, w = tid >> 6, lane = tid & 63;
    const int b = blockIdx.y, row0 = blockIdx.x * RB;

    for (int i = tid; i < RB * DH; i += 256) {
        int r = i >> 6, d = i & 63;
        Qs[r][d] = Q[((size_t)b * L + row0 + r) * DH + d];
    }
    float m[RW], l[RW], acc[RW];
    #pragma unroll
    for (int rr = 0; rr < RW; ++rr) { m[rr] = -1e30f; l[rr] = 0.f; acc[rr] = 0.f; }

    for (int k0 = 0; k0 < L; k0 += TK) {
        __syncthreads();
        for (int i = tid; i < TK * DH; i += 256) {
            int key = i >> 6, d = i & 63;
            Kt[key][d]  = K[((size_t)b * L + k0 + key) * DH + d];
            Vts[d][key] = V[((size_t)b * L + k0 + key) * DH + d];
        }
        if (tid < TK) Bs[tid] = (Mk[(size_t)b * L + k0 + tid] == 0) ? -1e30f : 0.f;
        __syncthreads();
        float s[RW];
        #pragma unroll
        for (int rr = 0; rr < RW; ++rr) s[rr] = 0.f;
        for (int d4 = 0; d4 < DH; d4 += 4) {
            float kv[4];
            #pragma unroll
            for (int j = 0; j < 4; ++j) kv[j] = Kt[lane][d4 + j];
            #pragma unroll
            for (int rr = 0; rr < RW; ++rr)
                #pragma unroll
                for (int j = 0; j < 4; ++j)
                    s[rr] += Qs[w * RW + rr][d4 + j] * kv[j];
        }
        float alpha[RW];
        #pragma unroll
        for (int rr = 0; rr < RW; ++rr) {
            float sv = s[rr] * 0.125f + Bs[lane];
            float t = sv;
            #pragma unroll
            for (int off = 1; off < 64; off <<= 1) t = fmaxf(t, __shfl_xor(t, off));
            float mnew = fmaxf(m[rr], t);
            alpha[rr] = __expf(fminf(m[rr] - mnew, 0.f));
            float p = __expf(fminf(sv - mnew, 0.f));
            Ps[w][rr][lane] = p;
            float su = p;
            #pragma unroll
            for (int off = 1; off < 64; off <<= 1) su += __shfl_xor(su, off);
            l[rr] = l[rr] * alpha[rr] + su;
            m[rr] = mnew;
        }
        __syncthreads();
        #pragma unroll
        for (int rr = 0; rr < RW; ++rr) acc[rr] *= alpha[rr];
        for (int k4 = 0; k4 < TK; k4 += 4) {
            float vv[4];
            #pragma unroll
            for (int j = 0; j < 4; ++j) vv[j] = Vts[lane][k4 + j];
            #pragma unroll
            for (int rr = 0; rr < RW; ++rr)
                #pragma unroll
                for (int j = 0; j < 4; ++j)
                    acc[rr] += Ps[w][rr][k4 + j] * vv[j];
        }
    }
    #pragma unroll
    for (int rr = 0; rr < RW; ++rr) {
        int row = row0 + w * RW + rr;
        O[((size_t)b * L + row) * DH + lane] = acc[rr] / fmaxf(l[rr], 1e-20f);
    }
}

extern "C" void kernel_launch(void* const* d_in, const int* in_sizes, int n_in,
                              void* d_out, int out_size, void* d_ws, size_t ws_size,
                              hipStream_t stream) {
    const float* Q = (const float*)d_in[0];
    const float* K = (const float*)d_in[1];
    const float* V = (const float*)d_in[2];
    const int*   M = (const int*)d_in[3];
    float*       O = (float*)d_out;

    const size_t elems     = (size_t)B_N * L * DH;             // 1,048,576
    const size_t bf16_need = elems * 2 * 3;                    // 6 MB
    const size_t acc_elems = (size_t)SPLIT * B_N * L * DH;     // 8,388,608 (bf16)
    const size_t ml_elems  = (size_t)SPLIT * B_N * L;          // 131,072 (fp32)
    const size_t full_need = bf16_need + acc_elems * 2 + ml_elems * 4;  // ~23.3 MB

    unsigned short* Qb = (unsigned short*)d_ws;
    unsigned short* Kb = Qb + elems;
    unsigned short* Vt = Kb + elems;

    if (ws_size >= full_need) {
        unsigned short* ACCp = Vt + elems;
        float*          Lp   = (float*)(ACCp + acc_elems);

        prepass3<<<dim3(L / 16, B_N), dim3(256), 0, stream>>>(Q, K, V, M, Qb, Kb, Vt);
        fa_pipe32<<<dim3(L / 128, B_N * SPLIT), dim3(256), 0, stream>>>(
            Qb, Kb, Vt, M, ACCp, Lp);
        fa_combine<<<dim3(L / 4, B_N), dim3(256), 0, stream>>>(ACCp, Lp, O);
    } else {
        fa_scalar<<<dim3(L / RB, B_N), dim3(256), 0, stream>>>(Q, K, V, M, O);
    }
}

// Round 7
// 94.054 us; speedup vs baseline: 1.0178x; 1.0178x over previous
//
#include <hip/hip_runtime.h>

// Round 24: counted-vmcnt pipeline (T3+T4) on the r22 base (93.3us, best).
// Evidence: r19 barrier-halving NULL, r22 traffic-halving +1.6, r23 SW-pipe
// NULL — m233's signature "every single-piece fix is null" => the stall is
// __syncthreads' s_waitcnt vmcnt(0) draining ALL in-flight global loads at
// every tile barrier (m97 mechanism). Fix: K/V LDS dbuf + ONE raw barrier
// per tile {lgkmcnt(0); sched_barrier; s_barrier; sched_barrier} with vmcnt
// NOT drained; two staging reg sets loaded 3 tiles ahead so the ds_write's
// compiler RAW wait is vmcnt(4) (t+2's loads stay flying across the barrier,
// never drain to 0 in the loop). Compute body/math byte-identical to r22
// (64q/wave, swapped QK^T, in-reg P via cvt_pk+permlane32_swap, mask folded
// into prepass). ~46us harness fill untouchable.
// C/D map: col=lane&31, row=(reg&3)+8(reg>>2)+4(lane>>5).
// B=4, Lq=Lk=4096, D=64, fp32 I/O, int32 key-padding mask.

#define B_N    4
#define L      4096
#define DH     64
#define TILE_K 64
#define KPAD   72
#define SPLIT  8
#define SLAB   (L / SPLIT)       // 512 keys per slab
#define TILES  (SLAB / TILE_K)   // 8 tiles per slab
#define QSCALE 0.18033688f       // 0.125 * log2(e); p = 2^(Qs K^T)

typedef unsigned short ushort8_ma __attribute__((ext_vector_type(8), may_alias));
typedef unsigned short ushort4_ma __attribute__((ext_vector_type(4), may_alias));
typedef float          f32x4_ma   __attribute__((ext_vector_type(4), may_alias));
typedef short          short8     __attribute__((ext_vector_type(8)));
typedef float          f32x16     __attribute__((ext_vector_type(16)));
typedef unsigned int   uint2_ev   __attribute__((ext_vector_type(2)));

union v8cast  { ushort8_ma u; short8 s; };
union pk4cast { unsigned int u[4]; short8 s; };

static __device__ __forceinline__ short8 ld8(const unsigned short* p) {
    v8cast x; x.u = *(const ushort8_ma*)p; return x.s;
}
static __device__ __forceinline__ unsigned short bf16rne(float f) {
    union { float f; unsigned u; } x; x.f = f;
    unsigned r = x.u + 0x7fffu + ((x.u >> 16) & 1u);
    return (unsigned short)(r >> 16);
}
static __device__ __forceinline__ float bf16tof(unsigned short u) {
    union { unsigned u; float f; } x; x.u = (unsigned)u << 16; return x.f;
}
static __device__ __forceinline__ float fast_exp2(float x) {
    return __builtin_amdgcn_exp2f(x);   // native v_exp_f32 (base-2)
}
static __device__ __forceinline__ unsigned cvt_pk_bf16(float lo, float hi) {
    unsigned r;                          // no builtin on gfx950 (m240) -> asm
    asm("v_cvt_pk_bf16_f32 %0, %1, %2" : "=v"(r) : "v"(lo), "v"(hi));
    return r;
}
// P A-fragment for one 8-value half of p (keys kk*16..+15): 4 cvt + 2 permlane.
static __device__ __forceinline__ short8 build_P(const f32x16& p, int b0) {
    unsigned A0 = cvt_pk_bf16(p[b0 + 0], p[b0 + 1]);
    unsigned A1 = cvt_pk_bf16(p[b0 + 2], p[b0 + 3]);
    unsigned B0 = cvt_pk_bf16(p[b0 + 4], p[b0 + 5]);
    unsigned B1 = cvt_pk_bf16(p[b0 + 6], p[b0 + 7]);
    uint2_ev r02 = __builtin_amdgcn_permlane32_swap(A0, B0, false, false);
    uint2_ev r13 = __builtin_amdgcn_permlane32_swap(A1, B1, false, false);
    pk4cast P;
    P.u[0] = r02[0]; P.u[1] = r13[0];   // j0..3 (hw'=0 source)
    P.u[2] = r02[1]; P.u[3] = r13[1];   // j4..7 (hw'=1 source)
    return P.s;
}

// ---- prepass: 16 rows/block: Qb=bf16(Q*QSCALE), Kb=bf16(K)*maskvalid,
//      Vt=bf16(V)*maskvalid transposed [b][d][key]. Masked key rows zeroed so
//      the main loop needs no mask: s==0 -> p==1, V==0 -> 0 numerator. ----
__global__ __launch_bounds__(256)
void prepass3(const float* __restrict__ Q, const float* __restrict__ K,
              const float* __restrict__ V, const int* __restrict__ M,
              unsigned short* __restrict__ Qb, unsigned short* __restrict__ Kb,
              unsigned short* __restrict__ Vt)
{
    __shared__ unsigned short t[64][20];   // [d][key16 + pad]
    const int b  = blockIdx.y;
    const int r0 = blockIdx.x * 16;
    const size_t base = ((size_t)b * L + r0) * DH;

    {
        int i = threadIdx.x;               // 256 = 16 rows x 16 float4
        int row = i >> 4, d0 = (i & 15) * 4;
        size_t off = base + (size_t)row * DH + d0;
        f32x4_ma q = *(const f32x4_ma*)(Q + off);
        f32x4_ma k = *(const f32x4_ma*)(K + off);
        f32x4_ma v = *(const f32x4_ma*)(V + off);
        const float zf = (M[(size_t)b * L + r0 + row] == 0) ? 0.f : 1.f;
        ushort4_ma qo, ko;
        #pragma unroll
        for (int j = 0; j < 4; ++j) {
            qo[j] = bf16rne(q[j] * QSCALE);
            ko[j] = bf16rne(k[j] * zf);
            t[d0 + j][row] = bf16rne(v[j] * zf);
        }
        *(ushort4_ma*)(Qb + off) = qo;
        *(ushort4_ma*)(Kb + off) = ko;
    }
    __syncthreads();
    {
        int i = threadIdx.x;               // 256 = 64 d x 4 ushort4
        int d = i >> 2, k4 = (i & 3) * 4;
        ushort4_ma vo = { t[d][k4], t[d][k4 + 1], t[d][k4 + 2], t[d][k4 + 3] };
        *(ushort4_ma*)(Vt + ((size_t)b * DH + d) * L + r0 + k4) = vo;
    }
}

// ---- split-K main: 32x32x16 MFMA, 256 threads (4 waves x 64 q-rows),
//      counted-vmcnt pipeline: raw barriers never drain vmcnt ----
__global__ __launch_bounds__(256, 2)   // VGPR <= 256, 2 blocks/CU (8 waves)
void fa_pipe64(const unsigned short* __restrict__ Qb,
               const unsigned short* __restrict__ Kb,
               const unsigned short* __restrict__ Vt,
               const int*            __restrict__ Mk,
               unsigned short* __restrict__ ACCp, float* __restrict__ Lp)
{
    __shared__ unsigned short Kl[2][TILE_K * KPAD];   // 2 x 9216 B [key][d]
    __shared__ unsigned short Vl[2][DH * KPAD];       // 2 x 9216 B [d][key]
    __shared__ int            cntw[4];                // per-wave masked counts
    // 36880 B/block -> 2 blocks/CU = 73.8 KB

    const int tid  = threadIdx.x;
    const int wave = tid >> 6;
    const int lane = tid & 63;
    const int l32  = lane & 31;
    const int hw   = lane >> 5;            // half-wave index

    const int b      = blockIdx.y & (B_N - 1);
    const int slab   = blockIdx.y >> 2;
    const int qblock = blockIdx.x * 256;   // 4 waves x 64 rows
    const int kbase  = slab * SLAB;
    const int qbase  = qblock + wave * 64;

    // Q fragments (B operand), two q-halves: lane l32 -> q-col, k = hw*8+j
    short8 q00, q01, q02, q03, q10, q11, q12, q13;
    {
        const unsigned short* qp0 = Qb + ((size_t)b * L + qbase + l32) * DH + hw * 8;
        const unsigned short* qp1 = qp0 + 32 * DH;
        q00 = ld8(qp0);      q01 = ld8(qp0 + 16);
        q02 = ld8(qp0 + 32); q03 = ld8(qp0 + 48);
        q10 = ld8(qp1);      q11 = ld8(qp1 + 16);
        q12 = ld8(qp1 + 32); q13 = ld8(qp1 + 48);
    }

    const unsigned short* Kbb = Kb + (size_t)b * L * DH;
    const unsigned short* Vtb = Vt + (size_t)b * DH * L;
    const int*            Mb  = Mk + (size_t)b * L;

    // staging: 2 chunks of 8 bf16 per thread for K and for V (r12-validated)
    const int c1 = tid + 256;
    const int r0 = tid >> 3, d0 = (tid & 7) * 8;
    const int r1 = c1 >> 3,  d1 = (c1 & 7) * 8;

    // two staging register sets: tile parity even -> A, odd -> B
    ushort8_ma kA0, kA1, vA0, vA1, kB0, kB1, vB0, vB1;

#define LOADSET(SK0, SK1, SV0, SV1, TAU) do {                                  \
        const int k0n_ = kbase + (TAU) * TILE_K;                               \
        SK0 = *(const ushort8_ma*)(Kbb + (size_t)(k0n_ + r0) * DH + d0);       \
        SK1 = *(const ushort8_ma*)(Kbb + (size_t)(k0n_ + r1) * DH + d1);       \
        SV0 = *(const ushort8_ma*)(Vtb + (size_t)r0 * L + k0n_ + d0);          \
        SV1 = *(const ushort8_ma*)(Vtb + (size_t)r1 * L + k0n_ + d1);          \
    } while (0)

#define WRITESET(BUF, SK0, SK1, SV0, SV1) do {                                 \
        *(ushort8_ma*)(&Kl[BUF][r0 * KPAD + d0]) = SK0;                        \
        *(ushort8_ma*)(&Kl[BUF][r1 * KPAD + d1]) = SK1;                        \
        *(ushort8_ma*)(&Vl[BUF][r0 * KPAD + d0]) = SV0;                        \
        *(ushort8_ma*)(&Vl[BUF][r1 * KPAD + d1]) = SV1;                        \
    } while (0)

// light barrier: ds ops drained + sync, vmcnt deliberately NOT drained
#define LBAR() do {                                                            \
        asm volatile("s_waitcnt lgkmcnt(0)" ::: "memory");                     \
        __builtin_amdgcn_sched_barrier(0);                                     \
        __builtin_amdgcn_s_barrier();                                          \
        __builtin_amdgcn_sched_barrier(0);                                     \
    } while (0)

    // prologue: tiles 0,1 loads; mask count; write tile0; reload set A (tile2)
    LOADSET(kA0, kA1, vA0, vA1, 0);
    LOADSET(kB0, kB1, vB0, vB1, 1);
    const int m0 = Mb[kbase + 2 * tid];
    const int m1 = Mb[kbase + 2 * tid + 1];
    WRITESET(0, kA0, kA1, vA0, vA1);       // compiler RAW wait: counted vmcnt
    LOADSET(kA0, kA1, vA0, vA1, 2);        // WAR vs pending ds_write: compiler
    {
        unsigned long long bm0 = __ballot(m0 == 0);
        unsigned long long bm1 = __ballot(m1 == 0);
        if (lane == 0) cntw[wave] = __popcll(bm0) + __popcll(bm1);
    }
    __syncthreads();   // prologue: full drain once (cold) — LDS[0]+cntw visible

    f32x16 a00 = {0}, a01 = {0}, a10 = {0}, a11 = {0};   // acc[qh][dh]
    float rA0 = 0.f, rA1 = 0.f, rA2 = 0.f, rA3 = 0.f;    // rowsum qh=0
    float rB0 = 0.f, rB1 = 0.f, rB2 = 0.f, rB3 = 0.f;    // rowsum qh=1

    #pragma unroll
    for (int t = 0; t < TILES; ++t) {
        const int cur = t & 1;

        // ---- compute tile t (r22 body, buffers indexed by cur) ----
        #pragma unroll
        for (int g = 0; g < 2; ++g) {
            const unsigned short* kp = &Kl[cur][(g * 32 + l32) * KPAD + hw * 8];
            short8 aK0 = ld8(kp);
            short8 aK1 = ld8(kp + 16);
            short8 aK2 = ld8(kp + 32);
            short8 aK3 = ld8(kp + 48);

            f32x16 s0 = {0}, s1 = {0};
            s0 = __builtin_amdgcn_mfma_f32_32x32x16_bf16(aK0, q00, s0, 0, 0, 0);
            s1 = __builtin_amdgcn_mfma_f32_32x32x16_bf16(aK0, q10, s1, 0, 0, 0);
            s0 = __builtin_amdgcn_mfma_f32_32x32x16_bf16(aK1, q01, s0, 0, 0, 0);
            s1 = __builtin_amdgcn_mfma_f32_32x32x16_bf16(aK1, q11, s1, 0, 0, 0);
            s0 = __builtin_amdgcn_mfma_f32_32x32x16_bf16(aK2, q02, s0, 0, 0, 0);
            s1 = __builtin_amdgcn_mfma_f32_32x32x16_bf16(aK2, q12, s1, 0, 0, 0);
            s0 = __builtin_amdgcn_mfma_f32_32x32x16_bf16(aK3, q03, s0, 0, 0, 0);
            s1 = __builtin_amdgcn_mfma_f32_32x32x16_bf16(aK3, q13, s1, 0, 0, 0);

            // lane holds P[q = qh*32+l32][key = g*32 + (reg&3)+8(reg>>2)+4hw]
            f32x16 p0, p1;
            #pragma unroll
            for (int r = 0; r < 16; r += 4) {
                p0[r + 0] = fast_exp2(s0[r + 0]); rA0 += p0[r + 0];
                p0[r + 1] = fast_exp2(s0[r + 1]); rA1 += p0[r + 1];
                p0[r + 2] = fast_exp2(s0[r + 2]); rA2 += p0[r + 2];
                p0[r + 3] = fast_exp2(s0[r + 3]); rA3 += p0[r + 3];
            }
            #pragma unroll
            for (int r = 0; r < 16; r += 4) {
                p1[r + 0] = fast_exp2(s1[r + 0]); rB0 += p1[r + 0];
                p1[r + 1] = fast_exp2(s1[r + 1]); rB1 += p1[r + 1];
                p1[r + 2] = fast_exp2(s1[r + 2]); rB2 += p1[r + 2];
                p1[r + 3] = fast_exp2(s1[r + 3]); rB3 += p1[r + 3];
            }
            #pragma unroll
            for (int h = 0; h < 2; ++h) {
                const int kk = 2 * g + h;      // K-slot: tile keys kk*16..+15
                const unsigned short* vp = &Vl[cur][l32 * KPAD + kk * 16 + hw * 8];
                short8 bV0 = ld8(vp);
                short8 bV1 = ld8(vp + 32 * KPAD);
                short8 P0 = build_P(p0, 8 * h);
                a00 = __builtin_amdgcn_mfma_f32_32x32x16_bf16(P0, bV0, a00, 0, 0, 0);
                a01 = __builtin_amdgcn_mfma_f32_32x32x16_bf16(P0, bV1, a01, 0, 0, 0);
                short8 P1 = build_P(p1, 8 * h);
                a10 = __builtin_amdgcn_mfma_f32_32x32x16_bf16(P1, bV0, a10, 0, 0, 0);
                a11 = __builtin_amdgcn_mfma_f32_32x32x16_bf16(P1, bV1, a11, 0, 0, 0);
            }
        }

        // ---- stage tile t+1 into buf nxt; one light barrier; refill t+3 ----
        if (t < TILES - 1) {
            const int nxt = cur ^ 1;
            if ((t + 1) & 1) WRITESET(nxt, kB0, kB1, vB0, vB1);
            else             WRITESET(nxt, kA0, kA1, vA0, vA1);
            LBAR();          // lgkmcnt(0) + s_barrier; vmcnt stays un-drained
            if (t + 3 < TILES) {
                if ((t + 3) & 1) LOADSET(kB0, kB1, vB0, vB1, t + 3);
                else             LOADSET(kA0, kA1, vA0, vA1, t + 3);
            }
        }
    }
#undef LOADSET
#undef WRITESET
#undef LBAR

    // epilogue: rowsum = in-lane sum + cross-halfwave add; subtract the slab's
    // masked-key count (each masked key contributed exactly 1.0).
    float rsA = (rA0 + rA1) + (rA2 + rA3);
    float rsB = (rB0 + rB1) + (rB2 + rB3);
    rsA += __shfl_xor(rsA, 32);
    rsB += __shfl_xor(rsB, 32);
    const float scnt = (float)(cntw[0] + cntw[1] + cntw[2] + cntw[3]);
    const size_t pbase = ((size_t)(slab * B_N + b)) * L;
    #pragma unroll
    for (int reg = 0; reg < 16; ++reg) {
        int row = (reg & 3) + 8 * (reg >> 2) + 4 * hw;
        unsigned short* ap0 = ACCp + (pbase + qbase + row) * DH;
        unsigned short* ap1 = ACCp + (pbase + qbase + 32 + row) * DH;
        ap0[l32]      = bf16rne(a00[reg]);
        ap0[32 + l32] = bf16rne(a01[reg]);
        ap1[l32]      = bf16rne(a10[reg]);
        ap1[32 + l32] = bf16rne(a11[reg]);
    }
    if (hw == 0) {
        Lp[pbase + qbase + l32]      = rsA - scnt;
        Lp[pbase + qbase + 32 + l32] = rsB - scnt;
    }
}

// ---- combine: plain sums over bf16 partials (fixed-m needs no max) ----
__global__ __launch_bounds__(256)
void fa_combine(const unsigned short* __restrict__ ACCp,
                const float* __restrict__ Lp, float* __restrict__ O)
{
    const int b    = blockIdx.y;
    const int qrow = blockIdx.x * 4 + (threadIdx.x >> 6);
    const int d    = threadIdx.x & 63;

    float lsum = 0.f, o = 0.f;
    #pragma unroll
    for (int s = 0; s < SPLIT; ++s) {
        lsum += Lp[((size_t)(s * B_N + b)) * L + qrow];
        o    += bf16tof(ACCp[(((size_t)(s * B_N + b)) * L + qrow) * DH + d]);
    }
    O[((size_t)b * L + qrow) * DH + d] = o / fmaxf(lsum, 1e-20f);
}

// ---- fallback: validated scalar kernel ----
#define TK  64
#define RW  4
#define RB  16
#define KST 67

__global__ __launch_bounds__(256)
void fa_scalar(const float* __restrict__ Q, const float* __restrict__ K,
               const float* __restrict__ V, const int* __restrict__ Mk,
               float* __restrict__ O)
{
    __shared__ float Kt[TK][KST];
    __shared__ float Vts[DH][KST];
    __shared__ float Qs[RB][DH];
    __shared__ float Ps[4][RW][TK];
    __shared__ float Bs[TK];

    const int tid = threadIdx.x, w = tid >> 6, lane = tid & 63;
    const int b = blockIdx.y, row0 = blockIdx.x * RB;

    for (int i = tid; i < RB * DH; i += 256) {
        int r = i >> 6, d = i & 63;
        Qs[r][d] = Q[((size_t)b * L + row0 + r) * DH + d];
    }
    float m[RW], l[RW], acc[RW];
    #pragma unroll
    for (int rr = 0; rr < RW; ++rr) { m[rr] = -1e30f; l[rr] = 0.f; acc[rr] = 0.f; }

    for (int k0 = 0; k0 < L; k0 += TK) {
        __syncthreads();
        for (int i = tid; i < TK * DH; i += 256) {
            int key = i >> 6, d = i & 63;
            Kt[key][d]  = K[((size_t)b * L + k0 + key) * DH + d];
            Vts[d][key] = V[((size_t)b * L + k0 + key) * DH + d];
        }
        if (tid < TK) Bs[tid] = (Mk[(size_t)b * L + k0 + tid] == 0) ? -1e30f : 0.f;
        __syncthreads();
        float s[RW];
        #pragma unroll
        for (int rr = 0; rr < RW; ++rr) s[rr] = 0.f;
        for (int d4 = 0; d4 < DH; d4 += 4) {
            float kv[4];
            #pragma unroll
            for (int j = 0; j < 4; ++j) kv[j] = Kt[lane][d4 + j];
            #pragma unroll
            for (int rr = 0; rr < RW; ++rr)
                #pragma unroll
                for (int j = 0; j < 4; ++j)
                    s[rr] += Qs[w * RW + rr][d4 + j] * kv[j];
        }
        float alpha[RW];
        #pragma unroll
        for (int rr = 0; rr < RW; ++rr) {
            float sv = s[rr] * 0.125f + Bs[lane];
            float t = sv;
            #pragma unroll
            for (int off = 1; off < 64; off <<= 1) t = fmaxf(t, __shfl_xor(t, off));
            float mnew = fmaxf(m[rr], t);
            alpha[rr] = __expf(fminf(m[rr] - mnew, 0.f));
            float p = __expf(fminf(sv - mnew, 0.f));
            Ps[w][rr][lane] = p;
            float su = p;
            #pragma unroll
            for (int off = 1; off < 64; off <<= 1) su += __shfl_xor(su, off);
            l[rr] = l[rr] * alpha[rr] + su;
            m[rr] = mnew;
        }
        __syncthreads();
        #pragma unroll
        for (int rr = 0; rr < RW; ++rr) acc[rr] *= alpha[rr];
        for (int k4 = 0; k4 < TK; k4 += 4) {
            float vv[4];
            #pragma unroll
            for (int j = 0; j < 4; ++j) vv[j] = Vts[lane][k4 + j];
            #pragma unroll
            for (int rr = 0; rr < RW; ++rr)
                #pragma unroll
                for (int j = 0; j < 4; ++j)
                    acc[rr] += Ps[w][rr][k4 + j] * vv[j];
        }
    }
    #pragma unroll
    for (int rr = 0; rr < RW; ++rr) {
        int row = row0 + w * RW + rr;
        O[((size_t)b * L + row) * DH + lane] = acc[rr] / fmaxf(l[rr], 1e-20f);
    }
}

extern "C" void kernel_launch(void* const* d_in, const int* in_sizes, int n_in,
                              void* d_out, int out_size, void* d_ws, size_t ws_size,
                              hipStream_t stream) {
    const float* Q = (const float*)d_in[0];
    const float* K = (const float*)d_in[1];
    const float* V = (const float*)d_in[2];
    const int*   M = (const int*)d_in[3];
    float*       O = (float*)d_out;

    const size_t elems     = (size_t)B_N * L * DH;             // 1,048,576
    const size_t bf16_need = elems * 2 * 3;                    // 6 MB
    const size_t acc_elems = (size_t)SPLIT * B_N * L * DH;     // 8,388,608 (bf16)
    const size_t ml_elems  = (size_t)SPLIT * B_N * L;          // 131,072 (fp32)
    const size_t full_need = bf16_need + acc_elems * 2 + ml_elems * 4;  // ~23.3 MB

    unsigned short* Qb = (unsigned short*)d_ws;
    unsigned short* Kb = Qb + elems;
    unsigned short* Vt = Kb + elems;

    if (ws_size >= full_need) {
        unsigned short* ACCp = Vt + elems;
        float*          Lp   = (float*)(ACCp + acc_elems);

        prepass3<<<dim3(L / 16, B_N), dim3(256), 0, stream>>>(Q, K, V, M, Qb, Kb, Vt);
        fa_pipe64<<<dim3(L / 256, B_N * SPLIT), dim3(256), 0, stream>>>(
            Qb, Kb, Vt, M, ACCp, Lp);
        fa_combine<<<dim3(L / 4, B_N), dim3(256), 0, stream>>>(ACCp, Lp, O);
    } else {
        fa_scalar<<<dim3(L / RB, B_N), dim3(256), 0, stream>>>(Q, K, V, M, O);
    }
}

// Round 8
// 92.964 us; speedup vs baseline: 1.0297x; 1.0117x over previous
//
#include <hip/hip_runtime.h>

// Round 25: SPLIT 8->4 on the r22 base (93.3us best; r22 body byte-identical).
// Rationale: r18-r24 span just 93.3-96.7 across radically different schedules
// -> schedule levers exhausted; remaining mechanical cost = SPLIT-scaled HBM
// traffic: ACCp 16MB written + 16MB re-read + Q 16MB re-read (~49MB, ~8us).
// SPLIT=4 halves all of it: slab=1024 keys, 16 tiles; grid (16,16)=256 blocks
// = 1 block/CU (4 waves). Occupancy record says OK (16->8 waves/CU IMPROVED,
// r18->r22). Mask prologue now 4 keys/thread (int4 + 4 ballots). Math
// unchanged (64q/wave, swapped QK^T s=mfma(K,Q), in-reg P via
// cvt_pk+permlane32_swap, mask folded into prepass: zeroed K/V rows -> p==1,
// subtract popcount from rowsum). Predict ~89-91us; if >=+2us regress,
// occupancy binds -> revert r22 and declare envelope. ~46us harness fill
// untouchable. C/D map: col=lane&31, row=(reg&3)+8(reg>>2)+4(lane>>5).
// B=4, Lq=Lk=4096, D=64, fp32 I/O, int32 key-padding mask.

#define B_N    4
#define L      4096
#define DH     64
#define TILE_K 64
#define KPAD   72
#define SPLIT  4
#define SLAB   (L / SPLIT)       // 1024 keys per slab
#define TILES  (SLAB / TILE_K)   // 16 tiles per slab
#define QSCALE 0.18033688f       // 0.125 * log2(e); p = 2^(Qs K^T)

typedef unsigned short ushort8_ma __attribute__((ext_vector_type(8), may_alias));
typedef unsigned short ushort4_ma __attribute__((ext_vector_type(4), may_alias));
typedef float          f32x4_ma   __attribute__((ext_vector_type(4), may_alias));
typedef short          short8     __attribute__((ext_vector_type(8)));
typedef float          f32x16     __attribute__((ext_vector_type(16)));
typedef unsigned int   uint2_ev   __attribute__((ext_vector_type(2)));
typedef int            int4_ma    __attribute__((ext_vector_type(4), may_alias));

union v8cast  { ushort8_ma u; short8 s; };
union pk4cast { unsigned int u[4]; short8 s; };

static __device__ __forceinline__ short8 ld8(const unsigned short* p) {
    v8cast x; x.u = *(const ushort8_ma*)p; return x.s;
}
static __device__ __forceinline__ unsigned short bf16rne(float f) {
    union { float f; unsigned u; } x; x.f = f;
    unsigned r = x.u + 0x7fffu + ((x.u >> 16) & 1u);
    return (unsigned short)(r >> 16);
}
static __device__ __forceinline__ float bf16tof(unsigned short u) {
    union { unsigned u; float f; } x; x.u = (unsigned)u << 16; return x.f;
}
static __device__ __forceinline__ float fast_exp2(float x) {
    return __builtin_amdgcn_exp2f(x);   // native v_exp_f32 (base-2)
}
static __device__ __forceinline__ unsigned cvt_pk_bf16(float lo, float hi) {
    unsigned r;                          // no builtin on gfx950 (m240) -> asm
    asm("v_cvt_pk_bf16_f32 %0, %1, %2" : "=v"(r) : "v"(lo), "v"(hi));
    return r;
}
// P A-fragment for one 8-value half of p (keys kk*16..+15): 4 cvt + 2 permlane.
static __device__ __forceinline__ short8 build_P(const f32x16& p, int b0) {
    unsigned A0 = cvt_pk_bf16(p[b0 + 0], p[b0 + 1]);
    unsigned A1 = cvt_pk_bf16(p[b0 + 2], p[b0 + 3]);
    unsigned B0 = cvt_pk_bf16(p[b0 + 4], p[b0 + 5]);
    unsigned B1 = cvt_pk_bf16(p[b0 + 6], p[b0 + 7]);
    uint2_ev r02 = __builtin_amdgcn_permlane32_swap(A0, B0, false, false);
    uint2_ev r13 = __builtin_amdgcn_permlane32_swap(A1, B1, false, false);
    pk4cast P;
    P.u[0] = r02[0]; P.u[1] = r13[0];   // j0..3 (hw'=0 source)
    P.u[2] = r02[1]; P.u[3] = r13[1];   // j4..7 (hw'=1 source)
    return P.s;
}

// ---- prepass: 16 rows/block: Qb=bf16(Q*QSCALE), Kb=bf16(K)*maskvalid,
//      Vt=bf16(V)*maskvalid transposed [b][d][key]. Masked key rows zeroed so
//      the main loop needs no mask: s==0 -> p==1, V==0 -> 0 numerator. ----
__global__ __launch_bounds__(256)
void prepass3(const float* __restrict__ Q, const float* __restrict__ K,
              const float* __restrict__ V, const int* __restrict__ M,
              unsigned short* __restrict__ Qb, unsigned short* __restrict__ Kb,
              unsigned short* __restrict__ Vt)
{
    __shared__ unsigned short t[64][20];   // [d][key16 + pad]
    const int b  = blockIdx.y;
    const int r0 = blockIdx.x * 16;
    const size_t base = ((size_t)b * L + r0) * DH;

    {
        int i = threadIdx.x;               // 256 = 16 rows x 16 float4
        int row = i >> 4, d0 = (i & 15) * 4;
        size_t off = base + (size_t)row * DH + d0;
        f32x4_ma q = *(const f32x4_ma*)(Q + off);
        f32x4_ma k = *(const f32x4_ma*)(K + off);
        f32x4_ma v = *(const f32x4_ma*)(V + off);
        const float zf = (M[(size_t)b * L + r0 + row] == 0) ? 0.f : 1.f;
        ushort4_ma qo, ko;
        #pragma unroll
        for (int j = 0; j < 4; ++j) {
            qo[j] = bf16rne(q[j] * QSCALE);
            ko[j] = bf16rne(k[j] * zf);
            t[d0 + j][row] = bf16rne(v[j] * zf);
        }
        *(ushort4_ma*)(Qb + off) = qo;
        *(ushort4_ma*)(Kb + off) = ko;
    }
    __syncthreads();
    {
        int i = threadIdx.x;               // 256 = 64 d x 4 ushort4
        int d = i >> 2, k4 = (i & 3) * 4;
        ushort4_ma vo = { t[d][k4], t[d][k4 + 1], t[d][k4 + 2], t[d][k4 + 3] };
        *(ushort4_ma*)(Vt + ((size_t)b * DH + d) * L + r0 + k4) = vo;
    }
}

// ---- split-K main: 32x32x16 MFMA, 256 threads (4 waves x 64 q-rows) ----
__global__ __launch_bounds__(256, 2)   // VGPR <= 256
void fa_split64(const unsigned short* __restrict__ Qb,
                const unsigned short* __restrict__ Kb,
                const unsigned short* __restrict__ Vt,
                const int*            __restrict__ Mk,
                unsigned short* __restrict__ ACCp, float* __restrict__ Lp)
{
    __shared__ unsigned short Kl[TILE_K * KPAD];   // 9216 B  [key][d]
    __shared__ unsigned short Vl[DH * KPAD];       // 9216 B  [d][key]
    __shared__ int            cntw[4];             // per-wave masked counts
    // 18688 B/block

    const int tid  = threadIdx.x;
    const int wave = tid >> 6;
    const int lane = tid & 63;
    const int l32  = lane & 31;
    const int hw   = lane >> 5;            // half-wave index

    const int b      = blockIdx.y & (B_N - 1);
    const int slab   = blockIdx.y >> 2;
    const int qblock = blockIdx.x * 256;   // 4 waves x 64 rows
    const int kbase  = slab * SLAB;
    const int qbase  = qblock + wave * 64;

    // Q fragments (B operand), two q-halves: lane l32 -> q-col, k = hw*8+j
    short8 q00, q01, q02, q03, q10, q11, q12, q13;
    {
        const unsigned short* qp0 = Qb + ((size_t)b * L + qbase + l32) * DH + hw * 8;
        const unsigned short* qp1 = qp0 + 32 * DH;
        q00 = ld8(qp0);      q01 = ld8(qp0 + 16);
        q02 = ld8(qp0 + 32); q03 = ld8(qp0 + 48);
        q10 = ld8(qp1);      q11 = ld8(qp1 + 16);
        q12 = ld8(qp1 + 32); q13 = ld8(qp1 + 48);
    }

    const unsigned short* Kbb = Kb + (size_t)b * L * DH;
    const unsigned short* Vtb = Vt + (size_t)b * DH * L;
    const int*            Mb  = Mk + (size_t)b * L;

    // staging: 2 chunks of 8 bf16 per thread for K and for V (r12-validated)
    const int c1 = tid + 256;
    const int r0 = tid >> 3, d0 = (tid & 7) * 8;
    const int r1 = c1 >> 3,  d1 = (c1 & 7) * 8;

    ushort8_ma kr0, kr1, vr0, vr1;

    kr0 = *(const ushort8_ma*)(Kbb + (size_t)(kbase + r0) * DH + d0);
    kr1 = *(const ushort8_ma*)(Kbb + (size_t)(kbase + r1) * DH + d1);
    vr0 = *(const ushort8_ma*)(Vtb + (size_t)r0 * L + kbase + d0);
    vr1 = *(const ushort8_ma*)(Vtb + (size_t)r1 * L + kbase + d1);
    // slab masked-key count: 1024 ints, 4/thread (int4), ballot+popcount
    const int4_ma mv = *(const int4_ma*)(Mb + kbase + 4 * tid);
    *(ushort8_ma*)(&Kl[r0 * KPAD + d0]) = kr0;
    *(ushort8_ma*)(&Kl[r1 * KPAD + d1]) = kr1;
    *(ushort8_ma*)(&Vl[r0 * KPAD + d0]) = vr0;
    *(ushort8_ma*)(&Vl[r1 * KPAD + d1]) = vr1;
    {
        unsigned long long bm0 = __ballot(mv[0] == 0);
        unsigned long long bm1 = __ballot(mv[1] == 0);
        unsigned long long bm2 = __ballot(mv[2] == 0);
        unsigned long long bm3 = __ballot(mv[3] == 0);
        if (lane == 0)
            cntw[wave] = __popcll(bm0) + __popcll(bm1) +
                         __popcll(bm2) + __popcll(bm3);
    }
    __syncthreads();

    f32x16 a00 = {0}, a01 = {0}, a10 = {0}, a11 = {0};   // acc[qh][dh]
    float rA0 = 0.f, rA1 = 0.f, rA2 = 0.f, rA3 = 0.f;    // rowsum qh=0
    float rB0 = 0.f, rB1 = 0.f, rB2 = 0.f, rB3 = 0.f;    // rowsum qh=1

    for (int t = 0; t < TILES; ++t) {
        if (t < TILES - 1) {    // next-tile loads in flight across compute
            const int k0n = kbase + (t + 1) * TILE_K;
            kr0 = *(const ushort8_ma*)(Kbb + (size_t)(k0n + r0) * DH + d0);
            kr1 = *(const ushort8_ma*)(Kbb + (size_t)(k0n + r1) * DH + d1);
            vr0 = *(const ushort8_ma*)(Vtb + (size_t)r0 * L + k0n + d0);
            vr1 = *(const ushort8_ma*)(Vtb + (size_t)r1 * L + k0n + d1);
        }

        // S^T (64 keys x 64 q-rows), one 32-key group at a time; aK and bV
        // LDS fragments shared by both q-halves (the traffic win).
        #pragma unroll
        for (int g = 0; g < 2; ++g) {
            const unsigned short* kp = &Kl[(g * 32 + l32) * KPAD + hw * 8];
            short8 aK0 = ld8(kp);
            short8 aK1 = ld8(kp + 16);
            short8 aK2 = ld8(kp + 32);
            short8 aK3 = ld8(kp + 48);

            f32x16 s0 = {0}, s1 = {0};
            s0 = __builtin_amdgcn_mfma_f32_32x32x16_bf16(aK0, q00, s0, 0, 0, 0);
            s1 = __builtin_amdgcn_mfma_f32_32x32x16_bf16(aK0, q10, s1, 0, 0, 0);
            s0 = __builtin_amdgcn_mfma_f32_32x32x16_bf16(aK1, q01, s0, 0, 0, 0);
            s1 = __builtin_amdgcn_mfma_f32_32x32x16_bf16(aK1, q11, s1, 0, 0, 0);
            s0 = __builtin_amdgcn_mfma_f32_32x32x16_bf16(aK2, q02, s0, 0, 0, 0);
            s1 = __builtin_amdgcn_mfma_f32_32x32x16_bf16(aK2, q12, s1, 0, 0, 0);
            s0 = __builtin_amdgcn_mfma_f32_32x32x16_bf16(aK3, q03, s0, 0, 0, 0);
            s1 = __builtin_amdgcn_mfma_f32_32x32x16_bf16(aK3, q13, s1, 0, 0, 0);

            // lane holds P[q = qh*32+l32][key = g*32 + (reg&3)+8(reg>>2)+4hw]
            f32x16 p0, p1;
            #pragma unroll
            for (int r = 0; r < 16; r += 4) {
                p0[r + 0] = fast_exp2(s0[r + 0]); rA0 += p0[r + 0];
                p0[r + 1] = fast_exp2(s0[r + 1]); rA1 += p0[r + 1];
                p0[r + 2] = fast_exp2(s0[r + 2]); rA2 += p0[r + 2];
                p0[r + 3] = fast_exp2(s0[r + 3]); rA3 += p0[r + 3];
            }
            #pragma unroll
            for (int r = 0; r < 16; r += 4) {
                p1[r + 0] = fast_exp2(s1[r + 0]); rB0 += p1[r + 0];
                p1[r + 1] = fast_exp2(s1[r + 1]); rB1 += p1[r + 1];
                p1[r + 2] = fast_exp2(s1[r + 2]); rB2 += p1[r + 2];
                p1[r + 3] = fast_exp2(s1[r + 3]); rB3 += p1[r + 3];
            }
            #pragma unroll
            for (int h = 0; h < 2; ++h) {
                const int kk = 2 * g + h;      // K-slot: tile keys kk*16..+15
                const unsigned short* vp = &Vl[l32 * KPAD + kk * 16 + hw * 8];
                short8 bV0 = ld8(vp);
                short8 bV1 = ld8(vp + 32 * KPAD);
                short8 P0 = build_P(p0, 8 * h);
                a00 = __builtin_amdgcn_mfma_f32_32x32x16_bf16(P0, bV0, a00, 0, 0, 0);
                a01 = __builtin_amdgcn_mfma_f32_32x32x16_bf16(P0, bV1, a01, 0, 0, 0);
                short8 P1 = build_P(p1, 8 * h);
                a10 = __builtin_amdgcn_mfma_f32_32x32x16_bf16(P1, bV0, a10, 0, 0, 0);
                a11 = __builtin_amdgcn_mfma_f32_32x32x16_bf16(P1, bV1, a11, 0, 0, 0);
            }
        }

        __syncthreads();                   // K/V readers done
        if (t < TILES - 1) {
            *(ushort8_ma*)(&Kl[r0 * KPAD + d0]) = kr0;
            *(ushort8_ma*)(&Kl[r1 * KPAD + d1]) = kr1;
            *(ushort8_ma*)(&Vl[r0 * KPAD + d0]) = vr0;
            *(ushort8_ma*)(&Vl[r1 * KPAD + d1]) = vr1;
            __syncthreads();               // writers done
        }
    }

    // epilogue: rowsum = in-lane sum + cross-halfwave add; subtract the slab's
    // masked-key count (each masked key contributed exactly 1.0).
    float rsA = (rA0 + rA1) + (rA2 + rA3);
    float rsB = (rB0 + rB1) + (rB2 + rB3);
    rsA += __shfl_xor(rsA, 32);
    rsB += __shfl_xor(rsB, 32);
    const float scnt = (float)(cntw[0] + cntw[1] + cntw[2] + cntw[3]);
    const size_t pbase = ((size_t)(slab * B_N + b)) * L;
    #pragma unroll
    for (int reg = 0; reg < 16; ++reg) {
        int row = (reg & 3) + 8 * (reg >> 2) + 4 * hw;
        unsigned short* ap0 = ACCp + (pbase + qbase + row) * DH;
        unsigned short* ap1 = ACCp + (pbase + qbase + 32 + row) * DH;
        ap0[l32]      = bf16rne(a00[reg]);
        ap0[32 + l32] = bf16rne(a01[reg]);
        ap1[l32]      = bf16rne(a10[reg]);
        ap1[32 + l32] = bf16rne(a11[reg]);
    }
    if (hw == 0) {
        Lp[pbase + qbase + l32]      = rsA - scnt;
        Lp[pbase + qbase + 32 + l32] = rsB - scnt;
    }
}

// ---- combine: plain sums over bf16 partials (fixed-m needs no max) ----
__global__ __launch_bounds__(256)
void fa_combine(const unsigned short* __restrict__ ACCp,
                const float* __restrict__ Lp, float* __restrict__ O)
{
    const int b    = blockIdx.y;
    const int qrow = blockIdx.x * 4 + (threadIdx.x >> 6);
    const int d    = threadIdx.x & 63;

    float lsum = 0.f, o = 0.f;
    #pragma unroll
    for (int s = 0; s < SPLIT; ++s) {
        lsum += Lp[((size_t)(s * B_N + b)) * L + qrow];
        o    += bf16tof(ACCp[(((size_t)(s * B_N + b)) * L + qrow) * DH + d]);
    }
    O[((size_t)b * L + qrow) * DH + d] = o / fmaxf(lsum, 1e-20f);
}

// ---- fallback: validated scalar kernel ----
#define TK  64
#define RW  4
#define RB  16
#define KST 67

__global__ __launch_bounds__(256)
void fa_scalar(const float* __restrict__ Q, const float* __restrict__ K,
               const float* __restrict__ V, const int* __restrict__ Mk,
               float* __restrict__ O)
{
    __shared__ float Kt[TK][KST];
    __shared__ float Vts[DH][KST];
    __shared__ float Qs[RB][DH];
    __shared__ float Ps[4][RW][TK];
    __shared__ float Bs[TK];

    const int tid = threadIdx.x, w = tid >> 6, lane = tid & 63;
    const int b = blockIdx.y, row0 = blockIdx.x * RB;

    for (int i = tid; i < RB * DH; i += 256) {
        int r = i >> 6, d = i & 63;
        Qs[r][d] = Q[((size_t)b * L + row0 + r) * DH + d];
    }
    float m[RW], l[RW], acc[RW];
    #pragma unroll
    for (int rr = 0; rr < RW; ++rr) { m[rr] = -1e30f; l[rr] = 0.f; acc[rr] = 0.f; }

    for (int k0 = 0; k0 < L; k0 += TK) {
        __syncthreads();
        for (int i = tid; i < TK * DH; i += 256) {
            int key = i >> 6, d = i & 63;
            Kt[key][d]  = K[((size_t)b * L + k0 + key) * DH + d];
            Vts[d][key] = V[((size_t)b * L + k0 + key) * DH + d];
        }
        if (tid < TK) Bs[tid] = (Mk[(size_t)b * L + k0 + tid] == 0) ? -1e30f : 0.f;
        __syncthreads();
        float s[RW];
        #pragma unroll
        for (int rr = 0; rr < RW; ++rr) s[rr] = 0.f;
        for (int d4 = 0; d4 < DH; d4 += 4) {
            float kv[4];
            #pragma unroll
            for (int j = 0; j < 4; ++j) kv[j] = Kt[lane][d4 + j];
            #pragma unroll
            for (int rr = 0; rr < RW; ++rr)
                #pragma unroll
                for (int j = 0; j < 4; ++j)
                    s[rr] += Qs[w * RW + rr][d4 + j] * kv[j];
        }
        float alpha[RW];
        #pragma unroll
        for (int rr = 0; rr < RW; ++rr) {
            float sv = s[rr] * 0.125f + Bs[lane];
            float t = sv;
            #pragma unroll
            for (int off = 1; off < 64; off <<= 1) t = fmaxf(t, __shfl_xor(t, off));
            float mnew = fmaxf(m[rr], t);
            alpha[rr] = __expf(fminf(m[rr] - mnew, 0.f));
            float p = __expf(fminf(sv - mnew, 0.f));
            Ps[w][rr][lane] = p;
            float su = p;
            #pragma unroll
            for (int off = 1; off < 64; off <<= 1) su += __shfl_xor(su, off);
            l[rr] = l[rr] * alpha[rr] + su;
            m[rr] = mnew;
        }
        __syncthreads();
        #pragma unroll
        for (int rr = 0; rr < RW; ++rr) acc[rr] *= alpha[rr];
        for (int k4 = 0; k4 < TK; k4 += 4) {
            float vv[4];
            #pragma unroll
            for (int j = 0; j < 4; ++j) vv[j] = Vts[lane][k4 + j];
            #pragma unroll
            for (int rr = 0; rr < RW; ++rr)
                #pragma unroll
                for (int j = 0; j < 4; ++j)
                    acc[rr] += Ps[w][rr][k4 + j] * vv[j];
        }
    }
    #pragma unroll
    for (int rr = 0; rr < RW; ++rr) {
        int row = row0 + w * RW + rr;
        O[((size_t)b * L + row) * DH + lane] = acc[rr] / fmaxf(l[rr], 1e-20f);
    }
}

extern "C" void kernel_launch(void* const* d_in, const int* in_sizes, int n_in,
                              void* d_out, int out_size, void* d_ws, size_t ws_size,
                              hipStream_t stream) {
    const float* Q = (const float*)d_in[0];
    const float* K = (const float*)d_in[1];
    const float* V = (const float*)d_in[2];
    const int*   M = (const int*)d_in[3];
    float*       O = (float*)d_out;

    const size_t elems     = (size_t)B_N * L * DH;             // 1,048,576
    const size_t bf16_need = elems * 2 * 3;                    // 6 MB
    const size_t acc_elems = (size_t)SPLIT * B_N * L * DH;     // 4,194,304 (bf16)
    const size_t ml_elems  = (size_t)SPLIT * B_N * L;          // 65,536 (fp32)
    const size_t full_need = bf16_need + acc_elems * 2 + ml_elems * 4;  // ~14.6 MB

    unsigned short* Qb = (unsigned short*)d_ws;
    unsigned short* Kb = Qb + elems;
    unsigned short* Vt = Kb + elems;

    if (ws_size >= full_need) {
        unsigned short* ACCp = Vt + elems;
        float*          Lp   = (float*)(ACCp + acc_elems);

        prepass3<<<dim3(L / 16, B_N), dim3(256), 0, stream>>>(Q, K, V, M, Qb, Kb, Vt);
        fa_split64<<<dim3(L / 256, B_N * SPLIT), dim3(256), 0, stream>>>(
            Qb, Kb, Vt, M, ACCp, Lp);
        fa_combine<<<dim3(L / 4, B_N), dim3(256), 0, stream>>>(ACCp, Lp, O);
    } else {
        fa_scalar<<<dim3(L / RB, B_N), dim3(256), 0, stream>>>(Q, K, V, M, O);
    }
}